// Round 3
// baseline (870.430 us; speedup 1.0000x reference)
//
#include <hip/hip_runtime.h>
#include <stdint.h>

#define D 512
#define NW 8
#define BATCH 8192
#define XROW 8704          // 17*D
#define BM 128
#define BK 64
#define MAT 262144         // 512*512

typedef __attribute__((ext_vector_type(8))) short bf16x8;
typedef __attribute__((ext_vector_type(4))) float f32x4;

struct Params {
  const float* x;
  const float* bq; const float* bkc;
  const float* bkp; const float* bkn;
  const float* bfp; const float* bfn;
  const float* bfc;
  const unsigned short* Wb;   // 35 bf16 512x512 matrices
  unsigned short* qw;         // q  bf16 [B][D]
  unsigned short* kcw;        // kc bf16 [B][D]
  float* ap; float* an;       // [B][8]
  float* xcn;                 // normalized center fp32 [B][D]
  float* out;
};

__device__ __forceinline__ unsigned short f2bf(float f) {
  union { float f; unsigned u; } v; v.f = f;
  unsigned u = v.u + 0x7FFFu + ((v.u >> 16) & 1u);   // RNE
  return (unsigned short)(u >> 16);
}
__device__ __forceinline__ float bf2f(unsigned short h) {
  union { unsigned u; float f; } v; v.u = ((unsigned)h) << 16;
  return v.f;
}

// K0: convert all weight matrices fp32 -> bf16 into ws (order:
// Wq, Wkc, Wkp[0..7], Wkn[0..7], Wfp[0..7], Wfn[0..7], Wfc)
__global__ void convert_weights(const float* Wq, const float* Wkc, const float* Wkp,
                                const float* Wkn, const float* Wfp, const float* Wfn,
                                const float* Wfc, unsigned short* outw) {
  const int total4 = 35 * MAT / 4;
  for (int i4 = blockIdx.x * blockDim.x + threadIdx.x; i4 < total4;
       i4 += gridDim.x * blockDim.x) {
    int idx = i4 * 4;
    int m = idx >> 18;
    int e = idx & (MAT - 1);
    const float* src;
    if (m == 0)       src = Wq + e;
    else if (m == 1)  src = Wkc + e;
    else if (m < 10)  src = Wkp + (size_t)(m - 2) * MAT + e;
    else if (m < 18)  src = Wkn + (size_t)(m - 10) * MAT + e;
    else if (m < 26)  src = Wfp + (size_t)(m - 18) * MAT + e;
    else if (m < 34)  src = Wfn + (size_t)(m - 26) * MAT + e;
    else              src = Wfc + e;
    float4 v = *reinterpret_cast<const float4*>(src);
    ushort4 o;
    o.x = f2bf(v.x); o.y = f2bf(v.y); o.z = f2bf(v.z); o.w = f2bf(v.w);
    *reinterpret_cast<ushort4*>(outw + idx) = o;
  }
}

// Batched GEMM, BM=128 x BN=512(full) x BK=64, 512 threads (8 waves, 2Mx4N),
// wave-tile 64x128, mfma_f32_16x16x32_bf16. Epilogues fused per unit.
//   epi 0: store q bf16   epi 1: store kc bf16
//   epi 2: l2norm row -> d_out (fp/fn)
//   epi 3: row-dot with q -> ap/an
//   epi 4: +bias +xc_orig(resid), l2norm -> d_out center (Wfc unit)
// LDS: Alds 16K + Blds 64K = 80 KiB exactly; `red` overlaps Alds (dead
// after the K-loop). XCD-chunked blockIdx swizzle (T1): all grids %8==0,
// so swz=(bid&7)*(nwg/8)+(bid>>3) is bijective; same-unit blocks land on
// one XCD -> each 512KB weight panel fetched by 1-2 XCD L2s, not all 8.
__launch_bounds__(512)
__global__ void gemm_mega(Params p, int launch_id) {
  __shared__ unsigned short Alds[BM * BK];   // 16 KB, XOR-swizzled; reused as red[] post-loop
  __shared__ unsigned short Blds[D * BK];    // 64 KB, XOR-swizzled

  const int nchunk = gridDim.x >> 3;         // gridDim.x % 8 == 0 for all launches
  const int swz  = (blockIdx.x & 7) * nchunk + (blockIdx.x >> 3);
  const int unit = swz >> 6;
  const int mb   = swz & 63;
  const int t    = threadIdx.x;
  const int lane = t & 63;
  const int wave = t >> 6;
  const int wm   = wave >> 2;   // 0..1  (64 rows each)
  const int wn   = wave & 3;    // 0..3  (128 cols each)

  const float* Aptr = p.x;
  int lda = XROW;
  int aofs = 0;
  const unsigned short* Wm = p.Wb;
  const float* bias = p.bq;
  int epi = 0;
  int outofs = 0;
  float* dotdst = nullptr;
  int wofs = 0;

  if (launch_id == 0) {
    if (unit == 0)      { aofs = 8 * D; Wm = p.Wb;            bias = p.bq;  epi = 0; }
    else if (unit == 1) { aofs = 8 * D; Wm = p.Wb + MAT;      bias = p.bkc; epi = 1; }
    else if (unit < 10) { int w = unit - 2;  aofs = w * D;
                          Wm = p.Wb + (size_t)(18 + w) * MAT; bias = p.bfp + w * D;
                          epi = 2; outofs = w * D; }
    else                { int w = unit - 10; aofs = (9 + w) * D;
                          Wm = p.Wb + (size_t)(26 + w) * MAT; bias = p.bfn + w * D;
                          epi = 2; outofs = (9 + w) * D; }
  } else if (launch_id == 1) {
    if (unit < 8) { int w = unit;     aofs = w * D;
                    Wm = p.Wb + (size_t)(2 + w) * MAT;  bias = p.bkp + w * D;
                    epi = 3; dotdst = p.ap; wofs = w; }
    else          { int w = unit - 8; aofs = (9 + w) * D;
                    Wm = p.Wb + (size_t)(10 + w) * MAT; bias = p.bkn + w * D;
                    epi = 3; dotdst = p.an; wofs = w; }
  } else {
    Aptr = p.xcn; lda = D; aofs = 0;
    Wm = p.Wb + (size_t)34 * MAT; bias = p.bfc; epi = 4; outofs = 8 * D;
  }

  const int row0 = mb * BM;

  f32x4 acc[4][8];
#pragma unroll
  for (int m = 0; m < 4; ++m)
#pragma unroll
    for (int n = 0; n < 8; ++n)
      acc[m][n] = (f32x4){0.f, 0.f, 0.f, 0.f};

  // A-staging mapping: thread -> (row, 16-elem k-chunk)
  const int ar = t >> 2;
  const int ak = (t & 3) * 16;
  const float* a_src = Aptr + (size_t)(row0 + ar) * lda + aofs + ak;

  char* albase = (char*)Alds;
  char* blbase = (char*)Blds;

  for (int kt = 0; kt < 8; ++kt) {
    const int k0 = kt * BK;
    // ---- stage A: fp32 load -> bf16 -> swizzled ds_write (2x16B) ----
    float4 av0 = *reinterpret_cast<const float4*>(a_src + k0);
    float4 av1 = *reinterpret_cast<const float4*>(a_src + k0 + 4);
    float4 av2 = *reinterpret_cast<const float4*>(a_src + k0 + 8);
    float4 av3 = *reinterpret_cast<const float4*>(a_src + k0 + 12);
    {
      bf16x8 pk;
      pk[0] = (short)f2bf(av0.x); pk[1] = (short)f2bf(av0.y);
      pk[2] = (short)f2bf(av0.z); pk[3] = (short)f2bf(av0.w);
      pk[4] = (short)f2bf(av1.x); pk[5] = (short)f2bf(av1.y);
      pk[6] = (short)f2bf(av1.z); pk[7] = (short)f2bf(av1.w);
      int bo = (ar << 7) + (ak << 1);
      *reinterpret_cast<bf16x8*>(albase + (bo ^ ((bo >> 3) & 0x70))) = pk;
      pk[0] = (short)f2bf(av2.x); pk[1] = (short)f2bf(av2.y);
      pk[2] = (short)f2bf(av2.z); pk[3] = (short)f2bf(av2.w);
      pk[4] = (short)f2bf(av3.x); pk[5] = (short)f2bf(av3.y);
      pk[6] = (short)f2bf(av3.z); pk[7] = (short)f2bf(av3.w);
      bo += 16;
      *reinterpret_cast<bf16x8*>(albase + (bo ^ ((bo >> 3) & 0x70))) = pk;
    }
    // ---- stage B: bf16 weights, global_load_lds 16B, pre-swizzled source
    //      (rule 21: linear LDS dest + inverse-swizzled global src + swizzled read) ----
#pragma unroll
    for (int i = 0; i < 8; ++i) {
      int o = i * 8192 + wave * 1024 + lane * 16;
      int Ls = o ^ ((o >> 3) & 0x70);   // involution: bits4-6 ^= bits7-9
      const unsigned short* src = Wm + (size_t)(Ls >> 7) * D + k0 + ((Ls & 127) >> 1);
      __builtin_amdgcn_global_load_lds(
          (const __attribute__((address_space(1))) unsigned*)src,
          (__attribute__((address_space(3))) unsigned*)(blbase + i * 8192 + wave * 1024),
          16, 0, 0);
    }
    __syncthreads();
    // ---- compute: 2 k-steps of 32, 64 MFMA per wave per kt ----
#pragma unroll
    for (int ks = 0; ks < 2; ++ks) {
      const int kb = ks * 64 + ((lane >> 4) << 4);   // byte offset of lane's k-slice
      bf16x8 af[4], bfr[8];
#pragma unroll
      for (int m = 0; m < 4; ++m) {
        int r = wm * 64 + m * 16 + (lane & 15);
        int bo = (r << 7) + kb;
        af[m] = *reinterpret_cast<const bf16x8*>(albase + (bo ^ ((bo >> 3) & 0x70)));
      }
#pragma unroll
      for (int n = 0; n < 8; ++n) {
        int r = wn * 128 + n * 16 + (lane & 15);
        int bo = (r << 7) + kb;
        bfr[n] = *reinterpret_cast<const bf16x8*>(blbase + (bo ^ ((bo >> 3) & 0x70)));
      }
#pragma unroll
      for (int m = 0; m < 4; ++m)
#pragma unroll
        for (int n = 0; n < 8; ++n)
          acc[m][n] = __builtin_amdgcn_mfma_f32_16x16x32_bf16(af[m], bfr[n], acc[m][n], 0, 0, 0);
    }
    __syncthreads();
  }

  // ---- epilogue (Alds dead from here; overlap the reduction buffer onto it) ----
  float* red = (float*)Alds;
  const int rj = (lane >> 4) * 4;
  const int cl = lane & 15;
  float bv[8];
#pragma unroll
  for (int n = 0; n < 8; ++n) bv[n] = bias[wn * 128 + n * 16 + cl];
#pragma unroll
  for (int m = 0; m < 4; ++m)
#pragma unroll
    for (int n = 0; n < 8; ++n)
#pragma unroll
      for (int j = 0; j < 4; ++j)
        acc[m][n][j] += bv[n];

  if (epi <= 1) {
    unsigned short* dst = (epi == 0) ? p.qw : p.kcw;
#pragma unroll
    for (int m = 0; m < 4; ++m)
#pragma unroll
      for (int j = 0; j < 4; ++j) {
        int r = wm * 64 + m * 16 + rj + j;
#pragma unroll
        for (int n = 0; n < 8; ++n) {
          int col = wn * 128 + n * 16 + cl;
          dst[(size_t)(row0 + r) * D + col] = f2bf(acc[m][n][j]);
        }
      }
  } else if (epi == 3) {
    if (t < BM) red[t] = 0.f;
    __syncthreads();
#pragma unroll
    for (int m = 0; m < 4; ++m)
#pragma unroll
      for (int j = 0; j < 4; ++j) {
        int r = wm * 64 + m * 16 + rj + j;
        float s = 0.f;
#pragma unroll
        for (int n = 0; n < 8; ++n) {
          int col = wn * 128 + n * 16 + cl;
          s += acc[m][n][j] * bf2f(p.qw[(size_t)(row0 + r) * D + col]);
        }
        s += __shfl_xor(s, 1); s += __shfl_xor(s, 2);
        s += __shfl_xor(s, 4); s += __shfl_xor(s, 8);
        if (cl == 0) atomicAdd(&red[r], s);
      }
    __syncthreads();
    if (t < BM) dotdst[(size_t)(row0 + t) * NW + wofs] = red[t];
  } else {
    if (epi == 4) {
#pragma unroll
      for (int m = 0; m < 4; ++m)
#pragma unroll
        for (int j = 0; j < 4; ++j) {
          int r = wm * 64 + m * 16 + rj + j;
#pragma unroll
          for (int n = 0; n < 8; ++n) {
            int col = wn * 128 + n * 16 + cl;
            acc[m][n][j] += p.x[(size_t)(row0 + r) * XROW + 8 * D + col];
          }
        }
    }
    if (t < BM) red[t] = 0.f;
    __syncthreads();
#pragma unroll
    for (int m = 0; m < 4; ++m)
#pragma unroll
      for (int j = 0; j < 4; ++j) {
        int r = wm * 64 + m * 16 + rj + j;
        float s = 0.f;
#pragma unroll
        for (int n = 0; n < 8; ++n) s += acc[m][n][j] * acc[m][n][j];
        s += __shfl_xor(s, 1); s += __shfl_xor(s, 2);
        s += __shfl_xor(s, 4); s += __shfl_xor(s, 8);
        if (cl == 0) atomicAdd(&red[r], s);
      }
    __syncthreads();
#pragma unroll
    for (int m = 0; m < 4; ++m)
#pragma unroll
      for (int j = 0; j < 4; ++j) {
        int r = wm * 64 + m * 16 + rj + j;
        float sc = 1.f / fmaxf(sqrtf(red[r]), 1e-12f);
#pragma unroll
        for (int n = 0; n < 8; ++n) {
          int col = wn * 128 + n * 16 + cl;
          p.out[(size_t)(row0 + r) * XROW + outofs + col] = acc[m][n][j] * sc;
        }
      }
  }
}

// K4: per-row combine: attn_c = q.kc ; xc_ = attn_c*xc + sum ap*xp + sum an*xn ;
// xcn = l2norm(xc_)
__launch_bounds__(128)
__global__ void combine(Params p) {
  __shared__ float sbuf[2];
  __shared__ float swt[16];
  const int b = blockIdx.x;
  const int t = threadIdx.x;    // 128 threads, 4 cols each
  const float* xrow = p.x + (size_t)b * XROW;

  const ushort4 q4 = reinterpret_cast<const ushort4*>(p.qw + (size_t)b * D)[t];
  const ushort4 c4 = reinterpret_cast<const ushort4*>(p.kcw + (size_t)b * D)[t];
  float s = bf2f(q4.x) * bf2f(c4.x) + bf2f(q4.y) * bf2f(c4.y) +
            bf2f(q4.z) * bf2f(c4.z) + bf2f(q4.w) * bf2f(c4.w);
  for (int m = 32; m >= 1; m >>= 1) s += __shfl_xor(s, m);
  if ((t & 63) == 0) sbuf[t >> 6] = s;
  if (t < 8)       swt[t] = p.ap[(size_t)b * NW + t];
  else if (t < 16) swt[t] = p.an[(size_t)b * NW + (t - 8)];
  __syncthreads();
  const float att = sbuf[0] + sbuf[1];

  float4 xc4 = reinterpret_cast<const float4*>(xrow + 8 * D)[t];
  float4 v;
  v.x = xc4.x * att; v.y = xc4.y * att; v.z = xc4.z * att; v.w = xc4.w * att;
#pragma unroll
  for (int w = 0; w < 8; ++w) {
    float aw = swt[w], nw2 = swt[8 + w];
    float4 xp4 = reinterpret_cast<const float4*>(xrow + w * D)[t];
    float4 xn4 = reinterpret_cast<const float4*>(xrow + (9 + w) * D)[t];
    v.x += aw * xp4.x + nw2 * xn4.x;
    v.y += aw * xp4.y + nw2 * xn4.y;
    v.z += aw * xp4.z + nw2 * xn4.z;
    v.w += aw * xp4.w + nw2 * xn4.w;
  }
  float ss = v.x * v.x + v.y * v.y + v.z * v.z + v.w * v.w;
  __syncthreads();   // sbuf reuse guard
  for (int m = 32; m >= 1; m >>= 1) ss += __shfl_xor(ss, m);
  if ((t & 63) == 0) sbuf[t >> 6] = ss;
  __syncthreads();
  float sc = 1.f / fmaxf(sqrtf(sbuf[0] + sbuf[1]), 1e-12f);
  float4 o; o.x = v.x * sc; o.y = v.y * sc; o.z = v.z * sc; o.w = v.w * sc;
  reinterpret_cast<float4*>(p.xcn + (size_t)b * D)[t] = o;
}

extern "C" void kernel_launch(void* const* d_in, const int* in_sizes, int n_in,
                              void* d_out, int out_size, void* d_ws, size_t ws_size,
                              hipStream_t stream) {
  const float* x   = (const float*)d_in[0];
  const float* Wq  = (const float*)d_in[1];
  const float* bq  = (const float*)d_in[2];
  const float* Wkc = (const float*)d_in[3];
  const float* bkc = (const float*)d_in[4];
  const float* Wkp = (const float*)d_in[5];
  const float* bkp = (const float*)d_in[6];
  const float* Wkn = (const float*)d_in[7];
  const float* bkn = (const float*)d_in[8];
  const float* Wfp = (const float*)d_in[9];
  const float* bfp = (const float*)d_in[10];
  const float* Wfn = (const float*)d_in[11];
  const float* bfn = (const float*)d_in[12];
  const float* Wfc = (const float*)d_in[13];
  const float* bfc = (const float*)d_in[14];

  char* ws = (char*)d_ws;
  unsigned short* Wb  = (unsigned short*)ws;              // 18,350,080 B
  unsigned short* qw  = (unsigned short*)(ws + 18350080); //  8,388,608 B
  unsigned short* kcw = (unsigned short*)(ws + 26738688); //  8,388,608 B
  float* ap  = (float*)(ws + 35127296);                   //    262,144 B
  float* an  = (float*)(ws + 35389440);                   //    262,144 B
  float* xcn = (float*)(ws + 35651584);                   // 16,777,216 B
  // total ws use: 52,428,800 B (50 MB)

  Params p { x, bq, bkc, bkp, bkn, bfp, bfn, bfc, Wb, qw, kcw, ap, an, xcn, (float*)d_out };

  hipLaunchKernelGGL(convert_weights, dim3(2048), dim3(256), 0, stream,
                     Wq, Wkc, Wkp, Wkn, Wfp, Wfn, Wfc, Wb);
  hipLaunchKernelGGL(gemm_mega, dim3(18 * 64), dim3(512), 0, stream, p, 0); // q,kc,fp,fn
  hipLaunchKernelGGL(gemm_mega, dim3(16 * 64), dim3(512), 0, stream, p, 1); // ap,an
  hipLaunchKernelGGL(combine,   dim3(8192),   dim3(128), 0, stream, p);     // xcn
  hipLaunchKernelGGL(gemm_mega, dim3(64),     dim3(512), 0, stream, p, 2);  // Wfc+resid
}